// Round 2
// baseline (6096.391 us; speedup 1.0000x reference)
//
#include <hip/hip_runtime.h>
#include <hip/hip_bf16.h>
#include <stdint.h>

#define NPTS 2048
#define DD 256

static constexpr long SZ_SB   = (long)DD * NPTS;       // [256][2048] block
static constexpr long SZ_SB2  = (long)512 * NPTS;      // [512][2048] block
static constexpr long SZ_S4   = (long)4 * NPTS * NPTS; // per-(s,b) scores, 4 heads
static constexpr long MB_ROW  = NPTS / 8;              // 256 bytes per bit-mask row
static constexpr long MB_B    = (long)NPTS * MB_ROW;   // per (type,b) mask
static constexpr long MB_T    = 2 * MB_B;              // per type

// ---------------------------------------------------------------------------
// fp32 GEMM: C[M,N] = W[M,K] @ X[K,N] + bias   (OP==1: C += ...)
// ---------------------------------------------------------------------------
template <int OP>
__global__ __launch_bounds__(256) void gemm_k(const float* __restrict__ W,
                                              const float* __restrict__ X,
                                              const float* __restrict__ bias,
                                              float* __restrict__ C,
                                              int M, int K, int N,
                                              long sW, long sX, long sC) {
  const int z = blockIdx.z;
  const float* Wp = W + (long)z * sW;
  const float* Xp = X + (long)z * sX;
  float* Cp = C + (long)z * sC;
  const int m0 = blockIdx.y * 64, n0 = blockIdx.x * 64;
  __shared__ __align__(16) float Ws[16][64];
  __shared__ __align__(16) float Xs[16][64];
  const int t = threadIdx.x;
  const int tx = t & 15, ty = t >> 4;
  const int wm = t >> 2, wk = (t & 3) * 4;
  const int xk = t >> 4, xn = (t & 15) * 4;
  float acc[4][4] = {};
  for (int k0 = 0; k0 < K; k0 += 16) {
    float4 w4 = *(const float4*)&Wp[(long)(m0 + wm) * K + k0 + wk];
    float4 x4 = *(const float4*)&Xp[(long)(k0 + xk) * N + n0 + xn];
    Ws[wk + 0][wm] = w4.x; Ws[wk + 1][wm] = w4.y;
    Ws[wk + 2][wm] = w4.z; Ws[wk + 3][wm] = w4.w;
    *(float4*)&Xs[xk][xn] = x4;
    __syncthreads();
#pragma unroll
    for (int k = 0; k < 16; ++k) {
      float4 a = *(const float4*)&Ws[k][ty * 4];
      float4 b = *(const float4*)&Xs[k][tx * 4];
      float av[4] = {a.x, a.y, a.z, a.w};
      float bv[4] = {b.x, b.y, b.z, b.w};
#pragma unroll
      for (int i = 0; i < 4; ++i)
#pragma unroll
        for (int j = 0; j < 4; ++j) acc[i][j] = fmaf(av[i], bv[j], acc[i][j]);
    }
    __syncthreads();
  }
#pragma unroll
  for (int i = 0; i < 4; ++i) {
    int m = m0 + ty * 4 + i;
    float bv = bias ? bias[m] : 0.f;
    float4 o = make_float4(acc[i][0] + bv, acc[i][1] + bv, acc[i][2] + bv, acc[i][3] + bv);
    float* cp = &Cp[(long)m * N + n0 + tx * 4];
    if (OP == 1) {
      float4 old = *(const float4*)cp;
      o.x += old.x; o.y += old.y; o.z += old.z; o.w += old.w;
    }
    *(float4*)cp = o;
  }
}

// ---------------------------------------------------------------------------
// scores for one (s,b): S[h][n][m] = maskbit ? (sum_hd Q[hd*4+h][n]*K[hd*4+h][m])/8 : 0
// grid (m/64, n/64, h)
// ---------------------------------------------------------------------------
__global__ __launch_bounds__(256) void score_k(const float* __restrict__ Qp,
                                               const float* __restrict__ Kp,
                                               const unsigned char* __restrict__ mb,
                                               float* __restrict__ S) {
  const int h = blockIdx.z;
  const int n0 = blockIdx.y * 64, m0 = blockIdx.x * 64;
  __shared__ __align__(16) float As[16][64];
  __shared__ __align__(16) float Bs[16][64];
  const int t = threadIdx.x, tx = t & 15, ty = t >> 4;
  const int lk = t >> 4, li = (t & 15) * 4;
  float acc[4][4] = {};
  for (int k0 = 0; k0 < 64; k0 += 16) {
    float4 a4 = *(const float4*)&Qp[(long)((k0 + lk) * 4 + h) * NPTS + n0 + li];
    float4 b4 = *(const float4*)&Kp[(long)((k0 + lk) * 4 + h) * NPTS + m0 + li];
    *(float4*)&As[lk][li] = a4;
    *(float4*)&Bs[lk][li] = b4;
    __syncthreads();
#pragma unroll
    for (int k = 0; k < 16; ++k) {
      float4 a = *(const float4*)&As[k][ty * 4];
      float4 b = *(const float4*)&Bs[k][tx * 4];
      float av[4] = {a.x, a.y, a.z, a.w};
      float bv[4] = {b.x, b.y, b.z, b.w};
#pragma unroll
      for (int i = 0; i < 4; ++i)
#pragma unroll
        for (int j = 0; j < 4; ++j) acc[i][j] = fmaf(av[i], bv[j], acc[i][j]);
    }
    __syncthreads();
  }
  float* Sz = S + (long)h * NPTS * NPTS;
#pragma unroll
  for (int i = 0; i < 4; ++i) {
    int n = n0 + ty * 4 + i;
    unsigned char byte = mb[(long)n * MB_ROW + (m0 >> 3) + (tx >> 1)];
    int nib = byte >> ((tx & 1) * 4);
    float4 o;
    o.x = (nib & 1) ? acc[i][0] * 0.125f : 0.f;
    o.y = (nib & 2) ? acc[i][1] * 0.125f : 0.f;
    o.z = (nib & 4) ? acc[i][2] * 0.125f : 0.f;
    o.w = (nib & 8) ? acc[i][3] * 0.125f : 0.f;
    *(float4*)&Sz[(long)n * NPTS + m0 + tx * 4] = o;
  }
}

// ---------------------------------------------------------------------------
// row softmax (4 heads of one (s,b,n)) in place + fused exact top-k prune:
// writes bit-mask row for the next same-type layer. knew==0 -> no prune.
// Tie semantics match jax.lax.top_k (lowest index first); masked entries of a
// row are exact fp32 ties so the tie-set matches the reference bit-for-bit.
// grid = 2048 rows
// ---------------------------------------------------------------------------
__global__ __launch_bounds__(256) void softmax_prune_k(float* __restrict__ S,
                                                       unsigned char* __restrict__ mb,
                                                       int knew) {
  const int t = threadIdx.x;
  const int n = blockIdx.x;
  __shared__ float r4[4];
  __shared__ unsigned int keys[2048];
  __shared__ int hist[256];
  __shared__ int sbb[2];
  __shared__ int sc[256];
  float mean[8] = {};
  for (int h = 0; h < 4; ++h) {
    float* row = S + ((long)h * NPTS + n) * NPTS;
    float v[8];
#pragma unroll
    for (int j = 0; j < 8; ++j) v[j] = row[t + j * 256];
    float mx = v[0];
#pragma unroll
    for (int j = 1; j < 8; ++j) mx = fmaxf(mx, v[j]);
    for (int o = 32; o; o >>= 1) mx = fmaxf(mx, __shfl_xor(mx, o));
    if ((t & 63) == 0) r4[t >> 6] = mx;
    __syncthreads();
    mx = fmaxf(fmaxf(r4[0], r4[1]), fmaxf(r4[2], r4[3]));
    __syncthreads();
    float e[8], s = 0.f;
#pragma unroll
    for (int j = 0; j < 8; ++j) { e[j] = __expf(v[j] - mx); s += e[j]; }
    for (int o = 32; o; o >>= 1) s += __shfl_xor(s, o);
    if ((t & 63) == 0) r4[t >> 6] = s;
    __syncthreads();
    s = r4[0] + r4[1] + r4[2] + r4[3];
    __syncthreads();
    const float ri = 1.0f / s;
#pragma unroll
    for (int j = 0; j < 8; ++j) {
      float p = e[j] * ri;
      row[t + j * 256] = p;
      mean[j] += 0.25f * p;
    }
  }
  if (knew == 0) return;
  // ---- exact top-k (radix select on monotone uint view; probs >= 0) ----
#pragma unroll
  for (int j = 0; j < 8; ++j) keys[t + j * 256] = __float_as_uint(mean[j]);
  unsigned int pref = 0;
  int kneed = knew;
  for (int pass = 0; pass < 4; ++pass) {
    const int shift = 24 - pass * 8;
    hist[t] = 0;
    __syncthreads();
    const unsigned int hm = (pass == 0) ? 0u : (0xFFFFFFFFu << (shift + 8));
#pragma unroll
    for (int j = 0; j < 8; ++j) {
      unsigned int key = keys[t * 8 + j];
      if ((key & hm) == pref) atomicAdd(&hist[(key >> shift) & 255], 1);
    }
    __syncthreads();
    if (t == 0) {
      int acc = 0, bin = 255;
      for (; bin > 0; --bin) {
        int c = hist[bin];
        if (acc + c >= kneed) break;
        acc += c;
      }
      sbb[0] = bin;
      sbb[1] = acc;
    }
    __syncthreads();
    pref |= ((unsigned int)sbb[0]) << shift;
    kneed -= sbb[1];
    __syncthreads();
  }
  const unsigned int T = pref;
  const int take = kneed;  // ties (== T) accepted, lowest index first
  int cnt = 0;
#pragma unroll
  for (int j = 0; j < 8; ++j) cnt += (keys[t * 8 + j] == T);
  sc[t] = cnt;
  __syncthreads();
  for (int off = 1; off < 256; off <<= 1) {
    int v = (t >= off) ? sc[t - off] : 0;
    __syncthreads();
    sc[t] += v;
    __syncthreads();
  }
  int base = sc[t] - cnt;
  unsigned int byte = 0;
#pragma unroll
  for (int j = 0; j < 8; ++j) {
    unsigned int key = keys[t * 8 + j];
    int sel = 0;
    if (key > T) sel = 1;
    else if (key == T) { if (T > 0u && base < take) sel = 1; base++; }
    byte |= (unsigned int)sel << j;
  }
  mb[(long)n * MB_ROW + t] = (unsigned char)byte;
}

// ---------------------------------------------------------------------------
// att[c=hd*4+h][n] = sum_m P[h][n][m] * V[c][m]     grid (n/64, 1, h)
// ---------------------------------------------------------------------------
__global__ __launch_bounds__(256) void pv_k(const float* __restrict__ S,
                                            const float* __restrict__ Vp,
                                            float* __restrict__ ap) {
  const int h = blockIdx.z;
  const float* Sz = S + (long)h * NPTS * NPTS;
  const int n0 = blockIdx.x * 64;
  __shared__ __align__(16) float As[16][64];  // [m-chunk][n]
  __shared__ __align__(16) float Bs[16][64];  // [m-chunk][hd]
  const int t = threadIdx.x, tx = t & 15, ty = t >> 4;
  const int ai = t >> 2, ak = (t & 3) * 4;
  const int bh = t & 63, bk = (t >> 6) * 4;
  float acc[4][4] = {};
  for (int m0 = 0; m0 < NPTS; m0 += 16) {
    float4 a4 = *(const float4*)&Sz[(long)(n0 + ai) * NPTS + m0 + ak];
    float4 b4 = *(const float4*)&Vp[(long)((bh << 2) + h) * NPTS + m0 + bk];
    As[ak + 0][ai] = a4.x; As[ak + 1][ai] = a4.y;
    As[ak + 2][ai] = a4.z; As[ak + 3][ai] = a4.w;
    Bs[bk + 0][bh] = b4.x; Bs[bk + 1][bh] = b4.y;
    Bs[bk + 2][bh] = b4.z; Bs[bk + 3][bh] = b4.w;
    __syncthreads();
#pragma unroll
    for (int k = 0; k < 16; ++k) {
      float4 a = *(const float4*)&As[k][ty * 4];
      float4 b = *(const float4*)&Bs[k][tx * 4];
      float av[4] = {a.x, a.y, a.z, a.w};
      float bv[4] = {b.x, b.y, b.z, b.w};
#pragma unroll
      for (int i = 0; i < 4; ++i)
#pragma unroll
        for (int j = 0; j < 4; ++j) acc[i][j] = fmaf(av[i], bv[j], acc[i][j]);
    }
    __syncthreads();
  }
#pragma unroll
  for (int j = 0; j < 4; ++j) {
    int c = ((tx * 4 + j) << 2) + h;
    float4 o = make_float4(acc[0][j], acc[1][j], acc[2][j], acc[3][j]);
    *(float4*)&ap[(long)c * NPTS + n0 + ty * 4] = o;
  }
}

// ---------------------------------------------------------------------------
__global__ __launch_bounds__(256) void instnorm_relu_k(float* __restrict__ X) {
  float* row = X + (long)blockIdx.x * NPTS;
  const int t = threadIdx.x;
  __shared__ float r8[8];
  float v[8], s = 0.f, s2 = 0.f;
#pragma unroll
  for (int j = 0; j < 8; ++j) {
    v[j] = row[t + j * 256];
    s += v[j];
    s2 = fmaf(v[j], v[j], s2);
  }
  for (int o = 32; o; o >>= 1) { s += __shfl_xor(s, o); s2 += __shfl_xor(s2, o); }
  if ((t & 63) == 0) { r8[t >> 6] = s; r8[4 + (t >> 6)] = s2; }
  __syncthreads();
  s = r8[0] + r8[1] + r8[2] + r8[3];
  s2 = r8[4] + r8[5] + r8[6] + r8[7];
  const float mu = s * (1.f / NPTS);
  const float var = s2 * (1.f / NPTS) - mu * mu;
  const float rs = rsqrtf(var + 1e-5f);
#pragma unroll
  for (int j = 0; j < 8; ++j) {
    float o = (v[j] - mu) * rs;
    row[t + j * 256] = o > 0.f ? o : 0.f;
  }
}

__global__ __launch_bounds__(256) void copyhalf_k(const float* __restrict__ src,
                                                  float* __restrict__ dst) {
  long fi = ((long)blockIdx.x * 256 + threadIdx.x) * 4;
  long b = fi >> 19;  // 256*2048 = 2^19
  long rem = fi & ((1L << 19) - 1);
  *(float4*)&dst[b * SZ_SB2 + rem] = *(const float4*)&src[fi];
}

// ---------------------------------------------------------------------------
extern "C" void kernel_launch(void* const* d_in, const int* in_sizes, int n_in,
                              void* d_out, int out_size, void* d_ws, size_t ws_size,
                              hipStream_t stream) {
  (void)in_sizes; (void)n_in; (void)out_size; (void)ws_size;
  const float* in_d0 = (const float*)d_in[0];
  const float* in_d1 = (const float*)d_in[1];
  const float* Wq = (const float*)d_in[2];
  const float* bq = (const float*)d_in[3];
  const float* Wk = (const float*)d_in[4];
  const float* bk = (const float*)d_in[5];
  const float* Wv = (const float*)d_in[6];
  const float* bv = (const float*)d_in[7];
  const float* Wm = (const float*)d_in[8];
  const float* bm = (const float*)d_in[9];
  const float* W1 = (const float*)d_in[10];
  const float* b1 = (const float*)d_in[11];
  const float* W2 = (const float*)d_in[12];
  const float* b2 = (const float*)d_in[13];

  float* desc = (float*)d_out;  // [stream s][batch b][256][2048]

  // ws layout (floats): Q,K,V,att (4*SZ_SB each) | S (4*N*N, overlaid with y+hb) | maskbits
  float* ws = (float*)d_ws;
  float* Q   = ws;
  float* Kb  = Q + 4 * SZ_SB;
  float* V   = Kb + 4 * SZ_SB;
  float* att = V + 4 * SZ_SB;
  float* S   = att + 4 * SZ_SB;        // 16,777,216 floats
  float* y   = S;                       // overlay: MLP phase only
  float* hb  = y + 4 * SZ_SB2;
  unsigned char* masks = (unsigned char*)(S + SZ_S4);  // 4 MB of bit-masks

  hipMemcpyAsync(desc, in_d0, 2 * SZ_SB * sizeof(float), hipMemcpyDeviceToDevice, stream);
  hipMemcpyAsync(desc + 2 * SZ_SB, in_d1, 2 * SZ_SB * sizeof(float), hipMemcpyDeviceToDevice, stream);
  hipMemsetAsync(masks, 0xFF, 4 * MB_T, stream);

  for (int l = 0; l < 6; ++l) {
    const bool selfl = (l % 2 == 0);
    // knew for the mask this layer's probs will produce (used at layer l+2)
    const int knew = (l <= 1) ? 1024 : (l <= 3) ? 512 : 0;

    // projections for all 4 (s,b) blocks
    dim3 gp(NPTS / 64, DD / 64, 4);
    gemm_k<0><<<gp, 256, 0, stream>>>(Wq + (long)l * 65536, desc, bq + l * 256, Q, DD, DD, NPTS, 0, SZ_SB, SZ_SB);
    gemm_k<0><<<gp, 256, 0, stream>>>(Wk + (long)l * 65536, desc, bk + l * 256, Kb, DD, DD, NPTS, 0, SZ_SB, SZ_SB);
    gemm_k<0><<<gp, 256, 0, stream>>>(Wv + (long)l * 65536, desc, bv + l * 256, V, DD, DD, NPTS, 0, SZ_SB, SZ_SB);

    // attention per (stream s, batch b)
    for (int s = 0; s < 2; ++s) {
      const int srcs = selfl ? s : 1 - s;
      const int type = selfl ? s : 2 + s;  // 00,11,01,10 -> 0,1,2,3
      for (int b = 0; b < 2; ++b) {
        unsigned char* mb = masks + (long)type * MB_T + (long)b * MB_B;
        score_k<<<dim3(NPTS / 64, NPTS / 64, 4), 256, 0, stream>>>(
            Q + ((long)s * 2 + b) * SZ_SB, Kb + ((long)srcs * 2 + b) * SZ_SB, mb, S);
        softmax_prune_k<<<dim3(NPTS), 256, 0, stream>>>(S, mb, knew);
        pv_k<<<dim3(NPTS / 64, 1, 4), 256, 0, stream>>>(
            S, V + ((long)srcs * 2 + b) * SZ_SB, att + ((long)s * 2 + b) * SZ_SB);
      }
    }

    // per-stream MLP + residual (y/hb overlay S: attention for this layer is done)
    for (int s = 0; s < 2; ++s) {
      copyhalf_k<<<dim3(1024), 256, 0, stream>>>(desc + (long)s * 2 * SZ_SB, y + (long)s * 2 * SZ_SB2);
      gemm_k<0><<<dim3(NPTS / 64, DD / 64, 2), 256, 0, stream>>>(
          Wm + (long)l * 65536, att + (long)s * 2 * SZ_SB, bm + l * 256,
          y + (long)s * 2 * SZ_SB2 + (long)DD * NPTS, DD, DD, NPTS, 0, SZ_SB, SZ_SB2);
      gemm_k<0><<<dim3(NPTS / 64, 512 / 64, 2), 256, 0, stream>>>(
          W1 + (long)l * 262144, y + (long)s * 2 * SZ_SB2, b1 + l * 512,
          hb + (long)s * 2 * SZ_SB2, 512, 512, NPTS, 0, SZ_SB2, SZ_SB2);
      instnorm_relu_k<<<dim3(1024), 256, 0, stream>>>(hb + (long)s * 2 * SZ_SB2);
      gemm_k<1><<<dim3(NPTS / 64, DD / 64, 2), 256, 0, stream>>>(
          W2 + (long)l * 131072, hb + (long)s * 2 * SZ_SB2, b2 + l * 256,
          desc + (long)s * 2 * SZ_SB, DD, 512, NPTS, 0, SZ_SB2, SZ_SB);
    }
  }
}